// Round 2
// baseline (487.341 us; speedup 1.0000x reference)
//
#include <hip/hip_runtime.h>
#include <hip/hip_bf16.h>

#define BLOCK 256

// Fused: per-row trapz integral of (y_pred - y_true) over [0, idx[b]],
// err_sq[b] = integral^2 -> ws; last block to finish reduces to mean.
__global__ __launch_bounds__(BLOCK) void strain_loss_kernel(
    const float* __restrict__ yp, const float* __restrict__ yt,
    const int* __restrict__ fidx, float* __restrict__ err_sq,
    unsigned int* __restrict__ done_ctr, float* __restrict__ out,
    int N, int B) {
    const int b = blockIdx.x;
    const float* __restrict__ p = yp + (size_t)b * N;
    const float* __restrict__ t = yt + (size_t)b * N;
    const int id = fidx[b];

    float sum = 0.0f;
    if (id > 0) {
        const int nchunk = (id >> 2) + 1;  // float4 chunks covering 0..id
        const float4* __restrict__ p4 = (const float4*)p;
        const float4* __restrict__ t4 = (const float4*)t;
        for (int c = threadIdx.x; c < nchunk; c += BLOCK) {
            const int j0 = c << 2;
            float4 a = p4[c];
            float4 q = t4[c];
            float d0 = a.x - q.x;
            float d1 = a.y - q.y;
            float d2 = a.z - q.z;
            float d3 = a.w - q.w;
            if (j0 + 3 <= id) {
                sum += (d0 + d1) + (d2 + d3);   // interior chunk: no branches
            } else {
                sum += d0;                       // j0 <= id guaranteed (c < nchunk)
                if (j0 + 1 <= id) sum += d1;
                if (j0 + 2 <= id) sum += d2;
            }
        }
    }

    // wave64 reduce
    for (int o = 32; o > 0; o >>= 1) sum += __shfl_down(sum, o);

    __shared__ float part[4];
    __shared__ int is_last;
    const int lane = threadIdx.x & 63;
    const int wid = threadIdx.x >> 6;
    if (lane == 0) part[wid] = sum;
    __syncthreads();
    if (threadIdx.x == 0) {
        float total = part[0] + part[1] + part[2] + part[3];
        if (id > 0) {
            // trapz: weights are 0.5 at ends, 1 inside -> subtract half-ends
            total -= 0.5f * ((p[0] - t[0]) + (p[id] - t[id]));
        }
        err_sq[b] = total * total;
        __threadfence();  // release err_sq[b] to device scope
        unsigned old = __hip_atomic_fetch_add(done_ctr, 1u, __ATOMIC_ACQ_REL,
                                              __HIP_MEMORY_SCOPE_AGENT);
        is_last = (old == (unsigned)(B - 1)) ? 1 : 0;
    }
    __syncthreads();

    if (is_last) {
        __threadfence();  // acquire: make all err_sq writes visible
        float s = 0.0f;
        for (int i = threadIdx.x; i < B; i += BLOCK) s += err_sq[i];
        for (int o = 32; o > 0; o >>= 1) s += __shfl_down(s, o);
        if (lane == 0) part[wid] = s;
        __syncthreads();
        if (threadIdx.x == 0) {
            out[0] = (part[0] + part[1] + part[2] + part[3]) / (float)B;
        }
    }
}

extern "C" void kernel_launch(void* const* d_in, const int* in_sizes, int n_in,
                              void* d_out, int out_size, void* d_ws, size_t ws_size,
                              hipStream_t stream) {
    const float* yp = (const float*)d_in[0];
    const float* yt = (const float*)d_in[1];
    const int* fidx = (const int*)d_in[2];
    float* out = (float*)d_out;

    const int B = in_sizes[2];           // 8192
    const int N = in_sizes[0] / B;       // 4096

    float* err_sq = (float*)d_ws;
    unsigned int* done_ctr = (unsigned int*)((float*)d_ws + B);

    hipMemsetAsync(done_ctr, 0, sizeof(unsigned int), stream);
    strain_loss_kernel<<<B, BLOCK, 0, stream>>>(yp, yt, fidx, err_sq, done_ctr,
                                                out, N, B);
}

// Round 3
// 28.631 us; speedup vs baseline: 17.0217x; 17.0217x over previous
//
#include <hip/hip_runtime.h>
#include <hip/hip_bf16.h>

#define BLOCK 256

// Kernel 1: one block per row. trapz integral of (y_pred - y_true) over
// [0, idx[b]] with unit spacing; err_sq[b] = integral^2 -> ws.
// Identity: integral = sum_{j=0..id} d_j - 0.5*(d_0 + d_id), so the bulk
// loop is branch-free; thread 0 applies the end correction.
__global__ __launch_bounds__(BLOCK) void row_integral_kernel(
    const float* __restrict__ yp, const float* __restrict__ yt,
    const int* __restrict__ fidx, float* __restrict__ err_sq, int N) {
    const int b = blockIdx.x;
    const float* __restrict__ p = yp + (size_t)b * N;
    const float* __restrict__ t = yt + (size_t)b * N;
    const int id = fidx[b];

    float sum = 0.0f;
    if (id > 0) {
        const int nchunk = (id >> 2) + 1;  // float4 chunks covering 0..id
        const float4* __restrict__ p4 = (const float4*)p;
        const float4* __restrict__ t4 = (const float4*)t;
        for (int c = threadIdx.x; c < nchunk; c += BLOCK) {
            const int j0 = c << 2;
            float4 a = p4[c];
            float4 q = t4[c];
            float d0 = a.x - q.x;
            float d1 = a.y - q.y;
            float d2 = a.z - q.z;
            float d3 = a.w - q.w;
            if (j0 + 3 <= id) {
                sum += (d0 + d1) + (d2 + d3);   // interior: branch-free
            } else {
                sum += d0;                       // j0 <= id guaranteed
                if (j0 + 1 <= id) sum += d1;
                if (j0 + 2 <= id) sum += d2;
            }
        }
    }

    // wave64 reduce
    for (int o = 32; o > 0; o >>= 1) sum += __shfl_down(sum, o);

    __shared__ float part[4];
    const int lane = threadIdx.x & 63;
    const int wid = threadIdx.x >> 6;
    if (lane == 0) part[wid] = sum;
    __syncthreads();
    if (threadIdx.x == 0) {
        float total = part[0] + part[1] + part[2] + part[3];
        if (id > 0) {
            total -= 0.5f * ((p[0] - t[0]) + (p[id] - t[id]));
        }
        err_sq[b] = total * total;
    }
}

// Kernel 2: single block, deterministic reduction of B floats -> mean.
__global__ __launch_bounds__(1024) void reduce_mean_kernel(
    const float* __restrict__ err_sq, float* __restrict__ out, int B) {
    const float4* __restrict__ e4 = (const float4*)err_sq;
    const int n4 = B >> 2;
    float s = 0.0f;
    for (int i = threadIdx.x; i < n4; i += 1024) {
        float4 v = e4[i];
        s += (v.x + v.y) + (v.z + v.w);
    }
    // tail (B not multiple of 4) — no-op for B=8192
    for (int i = (n4 << 2) + threadIdx.x; i < B; i += 1024) s += err_sq[i];

    for (int o = 32; o > 0; o >>= 1) s += __shfl_down(s, o);
    __shared__ float part[16];
    const int lane = threadIdx.x & 63;
    const int wid = threadIdx.x >> 6;
    if (lane == 0) part[wid] = s;
    __syncthreads();
    if (threadIdx.x == 0) {
        float total = 0.0f;
        for (int w = 0; w < 16; ++w) total += part[w];
        out[0] = total / (float)B;
    }
}

extern "C" void kernel_launch(void* const* d_in, const int* in_sizes, int n_in,
                              void* d_out, int out_size, void* d_ws, size_t ws_size,
                              hipStream_t stream) {
    const float* yp = (const float*)d_in[0];
    const float* yt = (const float*)d_in[1];
    const int* fidx = (const int*)d_in[2];
    float* out = (float*)d_out;
    float* err_sq = (float*)d_ws;

    const int B = in_sizes[2];           // 8192
    const int N = in_sizes[0] / B;       // 4096

    row_integral_kernel<<<B, BLOCK, 0, stream>>>(yp, yt, fidx, err_sq, N);
    reduce_mean_kernel<<<1, 1024, 0, stream>>>(err_sq, out, B);
}